// Round 4
// baseline (291.664 us; speedup 1.0000x reference)
//
#include <hip/hip_runtime.h>
#include <math.h>

#define B_ 2
#define H_ 16
#define S_ 2048
#define D_ 72
#define LP 576
#define WEND 1088
#define DP 96        // padded D for qn/kn (3 chunks of 32)
#define DV 80        // padded dims for Vt (5 tiles of 16)

// attn LDS layout (in 32-bit words)
#define KS 52                  // K row stride (96 bf16 + pad)
#define VS 36                  // V row stride (64 keys bf16 + pad)
#define PS 20                  // P row stride (32 bf16 + pad)
#define VBASE (64 * KS)        // 3328
#define PBASE (VBASE + DV * VS)// 6208
#define LDS_WORDS (PBASE + 2 * 32 * PS)  // 7488 words = 29952 B

#define NPREP (B_ * H_ * S_ / 4)   // 16384 blocks, 4 rows each
#define NVT   (32 * B_ * H_)       // 1024 blocks

typedef __bf16 bf16x8 __attribute__((ext_vector_type(8)));
typedef float f32x4 __attribute__((ext_vector_type(4)));

static __device__ __forceinline__ unsigned pack2bf(float a, float b) {
    __bf16 x = (__bf16)a, y = (__bf16)b;
    unsigned short ux = __builtin_bit_cast(unsigned short, x);
    unsigned short uy = __builtin_bit_cast(unsigned short, y);
    return (unsigned)ux | ((unsigned)uy << 16);
}

static __device__ __forceinline__ f32x4 mfma16(bf16x8 a, bf16x8 b, f32x4 c) {
    return __builtin_amdgcn_mfma_f32_16x16x32_bf16(a, b, c, 0, 0, 0);
}

// ---------- fused pre: prep (rotary+norm->bf16) | vtrans (+zero) ----------
__global__ __launch_bounds__(256) void pre_kernel(
    const float* __restrict__ q, const float* __restrict__ k,
    const float* __restrict__ v,
    const float* __restrict__ pos, const float* __restrict__ pos_orig,
    const float* __restrict__ time_, const float* __restrict__ freqs,
    const float* __restrict__ t_freqs, const float* __restrict__ scale,
    unsigned* __restrict__ qn, unsigned* __restrict__ kn,
    unsigned short* __restrict__ vt, float* __restrict__ out)
{
    __shared__ float tile[64 * 77];  // used by vtrans part only
    if (blockIdx.x < NPREP) {
        // ---- prep: one row per wave, branchless theta ----
        const int row = blockIdx.x * 4 + (threadIdx.x >> 6);
        const int t = threadIdx.x & 63;
        const int s = row & (S_ - 1);
        const int h = (row >> 11) & (H_ - 1);
        const int b = row >> 15;
        const long base = (long)row * D_;

        float q0v = 0.f, q1v = 0.f, k0v = 0.f, k1v = 0.f;
        if (t < 30) {
            const bool x1role = (t < 15);
            const int jj0 = x1role ? 2 * t : 2 * t - 30;
            const float2 qlo = *(const float2*)(q + base + jj0);
            const float2 qhi = *(const float2*)(q + base + jj0 + 30);
            const float2 klo = *(const float2*)(k + base + jj0);
            const float2 khi = *(const float2*)(k + base + jj0 + 30);
            const int p2 = (b * S_ + s) * 2;
            // all 5 base values, unconditionally (branchless)
            const float by_o = pos_orig[p2 + 1] * 2.f - 1.f;
            const float by_p = pos[p2 + 1]      * 2.f - 1.f;
            const float bx_o = pos_orig[p2 + 0] * 2.f - 1.f;
            const float bx_p = pos[p2 + 0]      * 2.f - 1.f;
            const float bt   = time_[b * S_ + s];
            float c0, s0, c1, s1;
            #pragma unroll
            for (int e = 0; e < 2; ++e) {
                const int jj = jj0 + e;
                const int g = jj / 6, i = jj - g * 6;
                const float fh = freqs[96 + h * 6 + i];
                const float fw = freqs[h * 6 + i];
                const float ft = t_freqs[h * 6 + i];
                const float f  = (g < 2) ? fh : ((g < 4) ? fw : ft);
                const float bv = (g == 0) ? by_o : (g == 1) ? by_p :
                                 (g == 2) ? bx_o : (g == 3) ? bx_p : bt;
                float cs, sn;
                __sincosf(bv * f, &sn, &cs);
                if (e == 0) { c0 = cs; s0 = sn; } else { c1 = cs; s1 = sn; }
            }
            if (x1role) {
                q0v = qlo.x * c0 - qhi.x * s0;  q1v = qlo.y * c1 - qhi.y * s1;
                k0v = klo.x * c0 - khi.x * s0;  k1v = klo.y * c1 - khi.y * s1;
            } else {
                q0v = qhi.x * c0 + qlo.x * s0;  q1v = qhi.y * c1 + qlo.y * s1;
                k0v = khi.x * c0 + klo.x * s0;  k1v = khi.y * c1 + klo.y * s1;
            }
        } else if (t < 36) {
            const float2 qv = *(const float2*)(q + base + 2 * t);
            const float2 kv = *(const float2*)(k + base + 2 * t);
            q0v = qv.x; q1v = qv.y; k0v = kv.x; k1v = kv.y;
        }
        float sq = q0v * q0v + q1v * q1v;
        float sk = k0v * k0v + k1v * k1v;
        #pragma unroll
        for (int m = 1; m < 64; m <<= 1) { sq += __shfl_xor(sq, m); sk += __shfl_xor(sk, m); }
        const float ss = sqrtf(scale[h]);
        const float fq = ss * rsqrtf(sq + 1e-6f);
        const float fk = ss * rsqrtf(sk + 1e-6f);
        const long obase = (long)row * 48;
        if (t < 36) {
            qn[obase + t] = pack2bf(q0v * fq, q1v * fq);
            kn[obase + t] = pack2bf(k0v * fk, k1v * fk);
        } else if (t < 39) {
            const uint4 z = make_uint4(0u, 0u, 0u, 0u);
            *(uint4*)(qn + obase + 36 + (t - 36) * 4) = z;
            *(uint4*)(kn + obase + 36 + (t - 36) * 4) = z;
        }
    } else {
        // ---- vtrans (+ zero of out rows < LP) ----
        const int bx2 = blockIdx.x - NPREP;
        const int st = bx2 & 31, bh = bx2 >> 5;
        const int s0 = st * 64;
        const int t = threadIdx.x;
        if (st < 9) {  // zero out[bh][s0..s0+64)
            float4* o4 = (float4*)(out + (long)(bh * S_ + s0) * D_);
            for (int i = t; i < 1152; i += 256) o4[i] = make_float4(0.f, 0.f, 0.f, 0.f);
        }
        for (int i = t; i < 1152; i += 256) {
            const int r = i / 18, c = i - r * 18;
            const float4 g = ((const float4*)v)[((long)(bh * S_ + s0 + r) * 18) + c];
            float* d = &tile[r * 77 + c * 4];
            d[0] = g.x; d[1] = g.y; d[2] = g.z; d[3] = g.w;
        }
        __syncthreads();
        for (int i = t; i < 1280; i += 256) {
            const int dd = i >> 4, s4 = i & 15;
            float f0 = 0.f, f1 = 0.f, f2 = 0.f, f3 = 0.f;
            if (dd < D_) {
                f0 = tile[(s4 * 4 + 0) * 77 + dd];
                f1 = tile[(s4 * 4 + 1) * 77 + dd];
                f2 = tile[(s4 * 4 + 2) * 77 + dd];
                f3 = tile[(s4 * 4 + 3) * 77 + dd];
            }
            uint2 o; o.x = pack2bf(f0, f1); o.y = pack2bf(f2, f3);
            ((uint2*)vt)[((((long)bh * DV + dd) << 11) + s0 + s4 * 4) >> 2] = o;
        }
    }
}

// ---------- attention: 32 q-rows/block, 2 waves split keys by parity ----------
__global__ __launch_bounds__(128) void attn_kernel(
    const unsigned short* __restrict__ qn, const unsigned short* __restrict__ kn,
    const unsigned short* __restrict__ vt, float* __restrict__ out)
{
    __shared__ __align__(16) unsigned lds[LDS_WORDS];
    const int bh = blockIdx.y;
    const int q0 = LP + blockIdx.x * 32;
    const int tid = threadIdx.x;
    const int w = tid >> 6, lane = tid & 63;
    const int quad = lane >> 4, l16 = lane & 15;
    const bool causal = (q0 < WEND);
    const int ntiles = causal ? ((q0 + 31) >> 5) + 1 : (WEND >> 5);
    const int npairs = (ntiles + 1) >> 1;

    const unsigned short* qn_b = qn + (((long)bh) << 11) * DP;
    const unsigned short* kn_b = kn + (((long)bh) << 11) * DP;
    const unsigned short* vt_b = vt + (long)bh * DV * S_;

    bf16x8 qf[2][3];
    #pragma unroll
    for (int m = 0; m < 2; ++m)
        #pragma unroll
        for (int c = 0; c < 3; ++c)
            qf[m][c] = *(const bf16x8*)(qn_b + (long)(q0 + m * 16 + l16) * DP + c * 32 + quad * 8);

    f32x4 o[2][5];
    float den[2][4];
    #pragma unroll
    for (int m = 0; m < 2; ++m) {
        #pragma unroll
        for (int dt = 0; dt < 5; ++dt) { o[m][dt][0]=0.f; o[m][dt][1]=0.f; o[m][dt][2]=0.f; o[m][dt][3]=0.f; }
        #pragma unroll
        for (int r = 0; r < 4; ++r) den[m][r] = 0.f;
    }

    unsigned* Ps = lds + PBASE + w * 640;

    for (int p = 0; p < npairs; ++p) {
        const int k0 = p * 64;
        // stage 64 keys of K (even/odd interleave per 32-group) + Vt
        for (int i = tid; i < 1408; i += 128) {
            if (i < 768) {
                const int r = i / 12, seg = i - r * 12;
                const int g = r >> 5, r32 = r & 31;
                const int key = k0 + 32 * g + 2 * (r32 & 15) + (r32 >> 4);
                *(uint4*)(lds + (32 * g + r32) * KS + seg * 4) =
                    *(const uint4*)(kn_b + (long)key * DP + seg * 8);
            } else {
                const int j = i - 768;
                const int row = j >> 3, seg = j & 7;
                *(uint4*)(lds + VBASE + row * VS + seg * 4) =
                    *(const uint4*)(vt_b + (((long)row) << 11) + k0 + seg * 8);
            }
        }
        __syncthreads();
        const int k0w = k0 + 32 * w;
        if (!causal || k0w <= q0 + 31) {
            f32x4 acc[2][2];
            #pragma unroll
            for (int m = 0; m < 2; ++m)
                #pragma unroll
                for (int n = 0; n < 2; ++n) { acc[m][n][0]=0.f; acc[m][n][1]=0.f; acc[m][n][2]=0.f; acc[m][n][3]=0.f; }
            #pragma unroll
            for (int c = 0; c < 3; ++c) {
                const bf16x8 kf0 = *(const bf16x8*)(lds + (32 * w + l16)      * KS + c * 16 + quad * 4);
                const bf16x8 kf1 = *(const bf16x8*)(lds + (32 * w + 16 + l16) * KS + c * 16 + quad * 4);
                acc[0][0] = mfma16(qf[0][c], kf0, acc[0][0]);
                acc[0][1] = mfma16(qf[0][c], kf1, acc[0][1]);
                acc[1][0] = mfma16(qf[1][c], kf0, acc[1][0]);
                acc[1][1] = mfma16(qf[1][c], kf1, acc[1][1]);
            }
            const int kb = k0w + 2 * l16;
            #pragma unroll
            for (int m = 0; m < 2; ++m) {
                #pragma unroll
                for (int r = 0; r < 4; ++r) {
                    const int qa = q0 + m * 16 + quad * 4 + r;
                    float p0 = acc[m][0][r], p1 = acc[m][1][r];
                    p0 = (!causal || kb     <= qa) ? __expf(p0) : 0.f;
                    p1 = (!causal || kb + 1 <= qa) ? __expf(p1) : 0.f;
                    const __bf16 pb0 = (__bf16)p0, pb1 = (__bf16)p1;
                    den[m][r] += (float)pb0 + (float)pb1;
                    unsigned pk = (unsigned)__builtin_bit_cast(unsigned short, pb0) |
                                  ((unsigned)__builtin_bit_cast(unsigned short, pb1) << 16);
                    Ps[(m * 16 + quad * 4 + r) * PS + l16] = pk;
                }
            }
            __builtin_amdgcn_sched_barrier(0);
            bf16x8 pa[2];
            pa[0] = *(const bf16x8*)(Ps + (l16)      * PS + quad * 4);
            pa[1] = *(const bf16x8*)(Ps + (16 + l16) * PS + quad * 4);
            #pragma unroll
            for (int dt = 0; dt < 5; ++dt) {
                const bf16x8 vf = *(const bf16x8*)(lds + VBASE + (dt * 16 + l16) * VS + w * 16 + quad * 4);
                o[0][dt] = mfma16(pa[0], vf, o[0][dt]);
                o[1][dt] = mfma16(pa[1], vf, o[1][dt]);
            }
        }
        __syncthreads();
    }

    // ---- combine the two parity waves' partials through LDS ----
    float* cb = (float*)lds;   // 64 lanes * 48 floats = 3072 words (< VBASE)
    if (w == 1) {
        const int basei = lane * 48;
        #pragma unroll
        for (int m = 0; m < 2; ++m) {
            #pragma unroll
            for (int dt = 0; dt < 5; ++dt)
                #pragma unroll
                for (int r = 0; r < 4; ++r) cb[basei + (m * 5 + dt) * 4 + r] = o[m][dt][r];
            #pragma unroll
            for (int r = 0; r < 4; ++r) cb[basei + 40 + m * 4 + r] = den[m][r];
        }
    }
    __syncthreads();
    if (w != 0) return;

    {
        const int basei = lane * 48;
        #pragma unroll
        for (int m = 0; m < 2; ++m) {
            #pragma unroll
            for (int dt = 0; dt < 5; ++dt)
                #pragma unroll
                for (int r = 0; r < 4; ++r) o[m][dt][r] += cb[basei + (m * 5 + dt) * 4 + r];
            #pragma unroll
            for (int r = 0; r < 4; ++r) den[m][r] += cb[basei + 40 + m * 4 + r];
        }
    }

    #pragma unroll
    for (int m = 0; m < 2; ++m)
        #pragma unroll
        for (int r = 0; r < 4; ++r)
            #pragma unroll
            for (int x = 1; x < 16; x <<= 1) den[m][r] += __shfl_xor(den[m][r], x);

    if (!causal) {  // diagonal self-key k == q (window rows)
        float* PsF = (float*)(lds + PBASE);
        #pragma unroll
        for (int m = 0; m < 2; ++m) {
            float sp = 0.f;
            #pragma unroll
            for (int c = 0; c < 3; ++c) {
                const bf16x8 kd = *(const bf16x8*)(kn_b + (long)(q0 + m * 16 + l16) * DP + c * 32 + quad * 8);
                #pragma unroll
                for (int j = 0; j < 8; ++j) sp += (float)qf[m][c][j] * (float)kd[j];
            }
            sp += __shfl_xor(sp, 16);
            sp += __shfl_xor(sp, 32);
            if (quad == 0) PsF[m * 16 + l16] = __expf(sp);
        }
        __builtin_amdgcn_sched_barrier(0);
        #pragma unroll
        for (int m = 0; m < 2; ++m)
            #pragma unroll
            for (int r = 0; r < 4; ++r) {
                const float pd = PsF[m * 16 + quad * 4 + r];
                den[m][r] += pd;
                const int qa = q0 + m * 16 + quad * 4 + r;
                #pragma unroll
                for (int dt = 0; dt < 5; ++dt) {
                    const unsigned short uv = vt_b[(((long)(dt * 16 + l16)) << 11) + qa];
                    o[m][dt][r] += pd * (float)__builtin_bit_cast(__bf16, uv);
                }
            }
    }

    #pragma unroll
    for (int m = 0; m < 2; ++m)
        #pragma unroll
        for (int r = 0; r < 4; ++r) {
            const float inv = 1.f / den[m][r];
            const int qa = q0 + m * 16 + quad * 4 + r;
            float* orow = out + ((long)(bh * S_ + qa)) * D_;
            #pragma unroll
            for (int dt = 0; dt < 5; ++dt) {
                const int dim = dt * 16 + l16;
                if (dim < D_) orow[dim] = o[m][dt][r] * inv;
            }
        }
}

extern "C" void kernel_launch(void* const* d_in, const int* in_sizes, int n_in,
                              void* d_out, int out_size, void* d_ws, size_t ws_size,
                              hipStream_t stream) {
    const float* q        = (const float*)d_in[0];
    const float* k        = (const float*)d_in[1];
    const float* v        = (const float*)d_in[2];
    const float* pos      = (const float*)d_in[3];
    const float* pos_orig = (const float*)d_in[4];
    const float* time_    = (const float*)d_in[5];
    const float* freqs    = (const float*)d_in[6];
    const float* t_freqs  = (const float*)d_in[7];
    const float* scale    = (const float*)d_in[8];
    float* out = (float*)d_out;

    unsigned* qn = (unsigned*)d_ws;
    unsigned* kn = qn + (size_t)B_ * H_ * S_ * 48;
    unsigned short* vt = (unsigned short*)(kn + (size_t)B_ * H_ * S_ * 48);

    pre_kernel<<<dim3(NPREP + NVT), dim3(256), 0, stream>>>(
        q, k, v, pos, pos_orig, time_, freqs, t_freqs, scale, qn, kn, vt, out);
    attn_kernel<<<dim3((S_ - LP) / 32, B_ * H_), dim3(128), 0, stream>>>(
        (const unsigned short*)qn, (const unsigned short*)kn, vt, out);
}

// Round 5
// 268.824 us; speedup vs baseline: 1.0850x; 1.0850x over previous
//
#include <hip/hip_runtime.h>
#include <math.h>

#define B_ 2
#define H_ 16
#define S_ 2048
#define D_ 72
#define LP 576
#define WEND 1088
#define DP 96        // padded D for qn/kn (3 chunks of 32)
#define DV 80        // padded dims for Vt (5 tiles of 16)
#define PW 20        // P LDS row stride in words

#define NPREP (B_ * H_ * S_ / 4)   // 16384 blocks, 4 rows each
#define NVT   (32 * B_ * H_)       // 1024 blocks

typedef __bf16 bf16x8 __attribute__((ext_vector_type(8)));
typedef float f32x4 __attribute__((ext_vector_type(4)));

static __device__ __forceinline__ unsigned pack2bf(float a, float b) {
    __bf16 x = (__bf16)a, y = (__bf16)b;
    unsigned short ux = __builtin_bit_cast(unsigned short, x);
    unsigned short uy = __builtin_bit_cast(unsigned short, y);
    return (unsigned)ux | ((unsigned)uy << 16);
}

static __device__ __forceinline__ f32x4 mfma16(bf16x8 a, bf16x8 b, f32x4 c) {
    return __builtin_amdgcn_mfma_f32_16x16x32_bf16(a, b, c, 0, 0, 0);
}

// ---------- fused pre: prep (rotary+norm->bf16) | vtrans (+zero) ----------
__global__ __launch_bounds__(256) void pre_kernel(
    const float* __restrict__ q, const float* __restrict__ k,
    const float* __restrict__ v,
    const float* __restrict__ pos, const float* __restrict__ pos_orig,
    const float* __restrict__ time_, const float* __restrict__ freqs,
    const float* __restrict__ t_freqs, const float* __restrict__ scale,
    unsigned* __restrict__ qn, unsigned* __restrict__ kn,
    unsigned short* __restrict__ vt, float* __restrict__ out)
{
    __shared__ float tile[64 * 77];  // used by vtrans part only
    if (blockIdx.x < NPREP) {
        // ---- prep: one row per wave, branchless theta ----
        const int row = blockIdx.x * 4 + (threadIdx.x >> 6);
        const int t = threadIdx.x & 63;
        const int s = row & (S_ - 1);
        const int h = (row >> 11) & (H_ - 1);
        const int b = row >> 15;
        const long base = (long)row * D_;

        float q0v = 0.f, q1v = 0.f, k0v = 0.f, k1v = 0.f;
        if (t < 30) {
            const bool x1role = (t < 15);
            const int jj0 = x1role ? 2 * t : 2 * t - 30;
            const float2 qlo = *(const float2*)(q + base + jj0);
            const float2 qhi = *(const float2*)(q + base + jj0 + 30);
            const float2 klo = *(const float2*)(k + base + jj0);
            const float2 khi = *(const float2*)(k + base + jj0 + 30);
            const int p2 = (b * S_ + s) * 2;
            const float by_o = pos_orig[p2 + 1] * 2.f - 1.f;
            const float by_p = pos[p2 + 1]      * 2.f - 1.f;
            const float bx_o = pos_orig[p2 + 0] * 2.f - 1.f;
            const float bx_p = pos[p2 + 0]      * 2.f - 1.f;
            const float bt   = time_[b * S_ + s];
            float c0, s0, c1, s1;
            #pragma unroll
            for (int e = 0; e < 2; ++e) {
                const int jj = jj0 + e;
                const int g = jj / 6, i = jj - g * 6;
                const float fh = freqs[96 + h * 6 + i];
                const float fw = freqs[h * 6 + i];
                const float ft = t_freqs[h * 6 + i];
                const float f  = (g < 2) ? fh : ((g < 4) ? fw : ft);
                const float bv = (g == 0) ? by_o : (g == 1) ? by_p :
                                 (g == 2) ? bx_o : (g == 3) ? bx_p : bt;
                float cs, sn;
                __sincosf(bv * f, &sn, &cs);
                if (e == 0) { c0 = cs; s0 = sn; } else { c1 = cs; s1 = sn; }
            }
            if (x1role) {
                q0v = qlo.x * c0 - qhi.x * s0;  q1v = qlo.y * c1 - qhi.y * s1;
                k0v = klo.x * c0 - khi.x * s0;  k1v = klo.y * c1 - khi.y * s1;
            } else {
                q0v = qhi.x * c0 + qlo.x * s0;  q1v = qhi.y * c1 + qlo.y * s1;
                k0v = khi.x * c0 + klo.x * s0;  k1v = khi.y * c1 + klo.y * s1;
            }
        } else if (t < 36) {
            const float2 qv = *(const float2*)(q + base + 2 * t);
            const float2 kv = *(const float2*)(k + base + 2 * t);
            q0v = qv.x; q1v = qv.y; k0v = kv.x; k1v = kv.y;
        }
        float sq = q0v * q0v + q1v * q1v;
        float sk = k0v * k0v + k1v * k1v;
        #pragma unroll
        for (int m = 1; m < 64; m <<= 1) { sq += __shfl_xor(sq, m); sk += __shfl_xor(sk, m); }
        const float ss = sqrtf(scale[h]);
        const float fq = ss * rsqrtf(sq + 1e-6f);
        const float fk = ss * rsqrtf(sk + 1e-6f);
        const long obase = (long)row * 48;
        if (t < 36) {
            qn[obase + t] = pack2bf(q0v * fq, q1v * fq);
            kn[obase + t] = pack2bf(k0v * fk, k1v * fk);
        } else if (t < 39) {
            const uint4 z = make_uint4(0u, 0u, 0u, 0u);
            *(uint4*)(qn + obase + 36 + (t - 36) * 4) = z;
            *(uint4*)(kn + obase + 36 + (t - 36) * 4) = z;
        }
    } else {
        // ---- vtrans (+ zero of out rows < LP) ----
        const int bx2 = blockIdx.x - NPREP;
        const int st = bx2 & 31, bh = bx2 >> 5;
        const int s0 = st * 64;
        const int t = threadIdx.x;
        if (st < 9) {  // zero out[bh][s0..s0+64)
            float4* o4 = (float4*)(out + (long)(bh * S_ + s0) * D_);
            for (int i = t; i < 1152; i += 256) o4[i] = make_float4(0.f, 0.f, 0.f, 0.f);
        }
        for (int i = t; i < 1152; i += 256) {
            const int r = i / 18, c = i - r * 18;
            const float4 g = ((const float4*)v)[((long)(bh * S_ + s0 + r) * 18) + c];
            float* d = &tile[r * 77 + c * 4];
            d[0] = g.x; d[1] = g.y; d[2] = g.z; d[3] = g.w;
        }
        __syncthreads();
        for (int i = t; i < 1280; i += 256) {
            const int dd = i >> 4, s4 = i & 15;
            float f0 = 0.f, f1 = 0.f, f2 = 0.f, f3 = 0.f;
            if (dd < D_) {
                f0 = tile[(s4 * 4 + 0) * 77 + dd];
                f1 = tile[(s4 * 4 + 1) * 77 + dd];
                f2 = tile[(s4 * 4 + 2) * 77 + dd];
                f3 = tile[(s4 * 4 + 3) * 77 + dd];
            }
            uint2 o; o.x = pack2bf(f0, f1); o.y = pack2bf(f2, f3);
            ((uint2*)vt)[((((long)bh * DV + dd) << 11) + s0 + s4 * 4) >> 2] = o;
        }
    }
}

// ---------- attention: 1 wave = 16 q-rows, barrier-free, direct global frags ----------
__global__ __launch_bounds__(64, 3) void attn_kernel(
    const unsigned short* __restrict__ qn, const unsigned short* __restrict__ kn,
    const unsigned short* __restrict__ vt, float* __restrict__ out)
{
    __shared__ __align__(16) unsigned Ps[16 * PW + 16];
    const int bh = blockIdx.y;
    const int q0 = LP + blockIdx.x * 16;
    const int lane = threadIdx.x & 63;
    const int quad = lane >> 4, l16 = lane & 15;
    const bool causal = (q0 < WEND);
    const int ntiles = causal ? ((q0 + 15) >> 5) + 1 : (WEND >> 5);

    const unsigned short* qn_b = qn + (((long)bh) << 11) * DP;
    const unsigned short* kn_b = kn + (((long)bh) << 11) * DP;
    const unsigned short* vt_b = vt + (long)bh * DV * S_;

    // A-fragments of Q: row m = l16, k-chunk c, k = quad*8+j
    bf16x8 qf[3];
    #pragma unroll
    for (int c = 0; c < 3; ++c)
        qf[c] = *(const bf16x8*)(qn_b + (long)(q0 + l16) * DP + c * 32 + quad * 8);

    // per-tile fragment base pointers
    const unsigned short* kp0 = kn_b + (long)(2 * l16) * DP + quad * 8;  // even key, +DP for odd
    const unsigned short* vp0 = vt_b + (((long)l16) << 11) + quad * 8;   // dim row, +dt*32768

    f32x4 o[5];
    float den[4];
    #pragma unroll
    for (int dt = 0; dt < 5; ++dt) { o[dt][0]=0.f; o[dt][1]=0.f; o[dt][2]=0.f; o[dt][3]=0.f; }
    #pragma unroll
    for (int r = 0; r < 4; ++r) den[r] = 0.f;

    auto loadT = [&](int t, bf16x8 kf[6], bf16x8 vf[5]) {
        const unsigned short* kp = kp0 + (long)t * 32 * DP;
        kf[0] = *(const bf16x8*)(kp);
        kf[1] = *(const bf16x8*)(kp + DP);
        kf[2] = *(const bf16x8*)(kp + 32);
        kf[3] = *(const bf16x8*)(kp + DP + 32);
        kf[4] = *(const bf16x8*)(kp + 64);
        kf[5] = *(const bf16x8*)(kp + DP + 64);
        const unsigned short* vp = vp0 + t * 32;
        #pragma unroll
        for (int dt = 0; dt < 5; ++dt)
            vf[dt] = *(const bf16x8*)(vp + dt * (16 << 11));
    };

    auto compute = [&](int t, const bf16x8 kf[6], const bf16x8 vf[5]) {
        f32x4 a0, a1;
        a0[0]=0.f;a0[1]=0.f;a0[2]=0.f;a0[3]=0.f;
        a1[0]=0.f;a1[1]=0.f;a1[2]=0.f;a1[3]=0.f;
        #pragma unroll
        for (int c = 0; c < 3; ++c) {
            a0 = mfma16(qf[c], kf[2 * c],     a0);
            a1 = mfma16(qf[c], kf[2 * c + 1], a1);
        }
        const int kb = t * 32 + 2 * l16;
        #pragma unroll
        for (int r = 0; r < 4; ++r) {
            const int qa = q0 + quad * 4 + r;
            float p0 = (!causal || kb     <= qa) ? __expf(a0[r]) : 0.f;
            float p1 = (!causal || kb + 1 <= qa) ? __expf(a1[r]) : 0.f;
            const __bf16 pb0 = (__bf16)p0, pb1 = (__bf16)p1;
            den[r] += (float)pb0 + (float)pb1;
            Ps[(quad * 4 + r) * PW + l16] =
                (unsigned)__builtin_bit_cast(unsigned short, pb0) |
                ((unsigned)__builtin_bit_cast(unsigned short, pb1) << 16);
        }
        const bf16x8 pa = *(const bf16x8*)(Ps + l16 * PW + quad * 4);
        #pragma unroll
        for (int dt = 0; dt < 5; ++dt)
            o[dt] = mfma16(pa, vf[dt], o[dt]);
    };

    // software-pipelined tile loop (ping-pong buffers, no barriers anywhere)
    bf16x8 kA[6], vA[5], kB[6], vB[5];
    loadT(0, kA, vA);
    int t = 0;
    while (true) {
        if (t + 1 < ntiles) loadT(t + 1, kB, vB);
        compute(t, kA, vA);
        ++t;
        if (t >= ntiles) break;
        if (t + 1 < ntiles) loadT(t + 1, kA, vA);
        compute(t, kB, vB);
        ++t;
        if (t >= ntiles) break;
    }

    // denominator: reduce across key-lanes (l16)
    #pragma unroll
    for (int r = 0; r < 4; ++r)
        #pragma unroll
        for (int x = 1; x < 16; x <<= 1) den[r] += __shfl_xor(den[r], x);

    if (!causal) {  // diagonal self-key k == q (window rows)
        float* PsD = (float*)(Ps + 16 * PW);
        float sp = 0.f;
        #pragma unroll
        for (int c = 0; c < 3; ++c) {
            const bf16x8 kd = *(const bf16x8*)(kn_b + (long)(q0 + l16) * DP + c * 32 + quad * 8);
            #pragma unroll
            for (int j = 0; j < 8; ++j) sp += (float)qf[c][j] * (float)kd[j];
        }
        sp += __shfl_xor(sp, 16);
        sp += __shfl_xor(sp, 32);
        if (quad == 0) PsD[l16] = __expf(sp);
        #pragma unroll
        for (int r = 0; r < 4; ++r) {
            const float pd = PsD[quad * 4 + r];
            den[r] += pd;
            const int qa = q0 + quad * 4 + r;
            #pragma unroll
            for (int dt = 0; dt < 5; ++dt) {
                const unsigned short uv = vt_b[(((long)(dt * 16 + l16)) << 11) + qa];
                o[dt][r] += pd * (float)__builtin_bit_cast(__bf16, uv);
            }
        }
    }

    #pragma unroll
    for (int r = 0; r < 4; ++r) {
        const float inv = 1.f / den[r];
        const int qa = q0 + quad * 4 + r;
        float* orow = out + ((long)(bh * S_ + qa)) * D_;
        #pragma unroll
        for (int dt = 0; dt < 5; ++dt) {
            const int dim = dt * 16 + l16;
            if (dim < D_) orow[dim] = o[dt][r] * inv;
        }
    }
}

extern "C" void kernel_launch(void* const* d_in, const int* in_sizes, int n_in,
                              void* d_out, int out_size, void* d_ws, size_t ws_size,
                              hipStream_t stream) {
    const float* q        = (const float*)d_in[0];
    const float* k        = (const float*)d_in[1];
    const float* v        = (const float*)d_in[2];
    const float* pos      = (const float*)d_in[3];
    const float* pos_orig = (const float*)d_in[4];
    const float* time_    = (const float*)d_in[5];
    const float* freqs    = (const float*)d_in[6];
    const float* t_freqs  = (const float*)d_in[7];
    const float* scale    = (const float*)d_in[8];
    float* out = (float*)d_out;

    unsigned* qn = (unsigned*)d_ws;
    unsigned* kn = qn + (size_t)B_ * H_ * S_ * 48;
    unsigned short* vt = (unsigned short*)(kn + (size_t)B_ * H_ * S_ * 48);

    pre_kernel<<<dim3(NPREP + NVT), dim3(256), 0, stream>>>(
        q, k, v, pos, pos_orig, time_, freqs, t_freqs, scale, qn, kn, vt, out);
    attn_kernel<<<dim3((S_ - LP) / 16, B_ * H_), dim3(64), 0, stream>>>(
        (const unsigned short*)qn, (const unsigned short*)kn, vt, out);
}

// Round 6
// 193.382 us; speedup vs baseline: 1.5082x; 1.3901x over previous
//
#include <hip/hip_runtime.h>
#include <math.h>

#define B_ 2
#define H_ 16
#define S_ 2048
#define D_ 72
#define LP 576
#define WEND 1088
#define DP 96        // padded D for qn/kn (3 chunks of 32)
#define DV 80        // padded dims for Vt (5 tiles of 16)

// attn LDS layout (32-bit words)
#define KS 50                    // K row stride (96 bf16 = 48 w + 2 pad)
#define VS 33                    // Vt row stride (64 bf16 = 32 w + 1 pad)
#define PW 33                    // P row stride (64 bf16 = 32 w + 1 pad)
#define VBASE (64 * KS)          // 3200
#define PBASE (VBASE + DV * VS)  // 3200 + 2640 = 5840
#define LDSW (PBASE + 4 * 16 * PW)  // 5840 + 2112 = 7952 words = 31808 B -> 5 blocks/CU

#define NPREP2 (B_ * H_ * S_ / 8)   // 8192 blocks, 8 rows each (2 rows/wave)
#define NVT    (32 * B_ * H_)       // 1024 blocks

typedef __bf16 bf16x8 __attribute__((ext_vector_type(8)));
typedef float f32x4 __attribute__((ext_vector_type(4)));

static __device__ __forceinline__ unsigned pack2bf(float a, float b) {
    __bf16 x = (__bf16)a, y = (__bf16)b;
    unsigned short ux = __builtin_bit_cast(unsigned short, x);
    unsigned short uy = __builtin_bit_cast(unsigned short, y);
    return (unsigned)ux | ((unsigned)uy << 16);
}

static __device__ __forceinline__ f32x4 mfma16(bf16x8 a, bf16x8 b, f32x4 c) {
    return __builtin_amdgcn_mfma_f32_16x16x32_bf16(a, b, c, 0, 0, 0);
}

// ---------- fused pre: prep (2 rows/wave, 1 sincos/pair) | vtrans (+zero) ----------
__global__ __launch_bounds__(256) void pre_kernel(
    const float* __restrict__ q, const float* __restrict__ k,
    const float* __restrict__ v,
    const float* __restrict__ pos, const float* __restrict__ pos_orig,
    const float* __restrict__ time_, const float* __restrict__ freqs,
    const float* __restrict__ t_freqs, const float* __restrict__ scale,
    unsigned* __restrict__ qn, unsigned* __restrict__ kn,
    unsigned short* __restrict__ vt, float* __restrict__ out)
{
    __shared__ float tile[64 * 77];  // vtrans branch only
    if (blockIdx.x < NPREP2) {
        const int wave = threadIdx.x >> 6;
        const int lane = threadIdx.x & 63;
        const int j = lane & 31;               // lane within row
        const int row = blockIdx.x * 8 + wave * 2 + (lane >> 5);
        const int s = row & (S_ - 1);
        const int h = (row >> 11) & (H_ - 1);
        const int b = row >> 15;
        const long base = (long)row * D_;
        const int p2 = (b * S_ + s) * 2;

        float oq1 = 0.f, oq2 = 0.f, ok1 = 0.f, ok2 = 0.f;
        float pq[6], pk[6];                    // passthrough lanes only
        float ssq = 0.f, ssk = 0.f;
        if (j < 30) {
            const float x1q = q[base + j], x2q = q[base + j + 30];
            const float x1k = k[base + j], x2k = k[base + j + 30];
            const int g = j / 6, i = j - 6 * g;
            const float fh = freqs[96 + h * 6 + i];
            const float fw = freqs[h * 6 + i];
            const float ft = t_freqs[h * 6 + i];
            const float f  = (g < 2) ? fh : ((g < 4) ? fw : ft);
            const float by_o = pos_orig[p2 + 1] * 2.f - 1.f;
            const float by_p = pos[p2 + 1]      * 2.f - 1.f;
            const float bx_o = pos_orig[p2 + 0] * 2.f - 1.f;
            const float bx_p = pos[p2 + 0]      * 2.f - 1.f;
            const float bt   = time_[b * S_ + s];
            const float bv = (g == 0) ? by_o : (g == 1) ? by_p :
                             (g == 2) ? bx_o : (g == 3) ? bx_p : bt;
            float sn, cs;
            __sincosf(bv * f, &sn, &cs);
            oq1 = x1q * cs - x2q * sn;  oq2 = x2q * cs + x1q * sn;
            ok1 = x1k * cs - x2k * sn;  ok2 = x2k * cs + x1k * sn;
            ssq = oq1 * oq1 + oq2 * oq2;
            ssk = ok1 * ok1 + ok2 * ok2;
        } else {
            const int e0 = 60 + 6 * (j - 30);
            #pragma unroll
            for (int m = 0; m < 3; ++m) {
                const float2 a = *(const float2*)(q + base + e0 + 2 * m);
                const float2 c = *(const float2*)(k + base + e0 + 2 * m);
                pq[2 * m] = a.x; pq[2 * m + 1] = a.y;
                pk[2 * m] = c.x; pk[2 * m + 1] = c.y;
                ssq += a.x * a.x + a.y * a.y;
                ssk += c.x * c.x + c.y * c.y;
            }
        }
        #pragma unroll
        for (int m = 1; m < 32; m <<= 1) { ssq += __shfl_xor(ssq, m); ssk += __shfl_xor(ssk, m); }
        const float ss = sqrtf(scale[h]);
        const float fq = ss * rsqrtf(ssq + 1e-6f);
        const float fk = ss * rsqrtf(ssk + 1e-6f);

        unsigned short* qs = (unsigned short*)qn;
        unsigned short* ks = (unsigned short*)kn;
        const long rb = (long)row * DP;
        if (j < 30) {
            qs[rb + j]      = __builtin_bit_cast(unsigned short, (__bf16)(oq1 * fq));
            qs[rb + j + 30] = __builtin_bit_cast(unsigned short, (__bf16)(oq2 * fq));
            ks[rb + j]      = __builtin_bit_cast(unsigned short, (__bf16)(ok1 * fk));
            ks[rb + j + 30] = __builtin_bit_cast(unsigned short, (__bf16)(ok2 * fk));
            if (j >= 26 && j < 29) {  // zero-pad elements 72..95 (3 uint4)
                const uint4 z = make_uint4(0u, 0u, 0u, 0u);
                *(uint4*)(qn + row * 48 + 36 + (j - 26) * 4) = z;
                *(uint4*)(kn + row * 48 + 36 + (j - 26) * 4) = z;
            }
        } else {
            const int u0 = row * 48 + 30 + 3 * (j - 30);
            #pragma unroll
            for (int m = 0; m < 3; ++m) {
                qn[u0 + m] = pack2bf(pq[2 * m] * fq, pq[2 * m + 1] * fq);
                kn[u0 + m] = pack2bf(pk[2 * m] * fk, pk[2 * m + 1] * fk);
            }
        }
    } else {
        // ---- vtrans (+ zero of out rows < LP) ----
        const int bx2 = blockIdx.x - NPREP2;
        const int st = bx2 & 31, bh = bx2 >> 5;
        const int s0 = st * 64;
        const int t = threadIdx.x;
        if (st < 9) {
            float4* o4 = (float4*)(out + (long)(bh * S_ + s0) * D_);
            for (int i = t; i < 1152; i += 256) o4[i] = make_float4(0.f, 0.f, 0.f, 0.f);
        }
        for (int i = t; i < 1152; i += 256) {
            const int r = i / 18, c = i - r * 18;
            const float4 g = ((const float4*)v)[((long)(bh * S_ + s0 + r) * 18) + c];
            float* d = &tile[r * 77 + c * 4];
            d[0] = g.x; d[1] = g.y; d[2] = g.z; d[3] = g.w;
        }
        __syncthreads();
        for (int i = t; i < 1280; i += 256) {
            const int dd = i >> 4, s4 = i & 15;
            float f0 = 0.f, f1 = 0.f, f2 = 0.f, f3 = 0.f;
            if (dd < D_) {
                f0 = tile[(s4 * 4 + 0) * 77 + dd];
                f1 = tile[(s4 * 4 + 1) * 77 + dd];
                f2 = tile[(s4 * 4 + 2) * 77 + dd];
                f3 = tile[(s4 * 4 + 3) * 77 + dd];
            }
            uint2 o; o.x = pack2bf(f0, f1); o.y = pack2bf(f2, f3);
            ((uint2*)vt)[((((long)bh * DV + dd) << 11) + s0 + s4 * 4) >> 2] = o;
        }
    }
}

// ---------- attention: 4 waves x 16 q-rows, 64-key LDS tiles ----------
__global__ __launch_bounds__(256) void attn_kernel(
    const unsigned short* __restrict__ qn, const unsigned short* __restrict__ kn,
    const unsigned short* __restrict__ vt, float* __restrict__ out)
{
    __shared__ __align__(16) unsigned lds[LDSW];
    const int bh = blockIdx.y;
    const int q0 = LP + blockIdx.x * 64;
    const int tid = threadIdx.x;
    const int w = tid >> 6, lane = tid & 63;
    const int quad = lane >> 4, l16 = lane & 15;
    const int q0w = q0 + 16 * w;
    const bool causal = (q0 < WEND);
    const int ntiles = causal ? (q0 >> 6) + 1 : (WEND >> 6);

    const unsigned short* qn_b = qn + (((long)bh) << 11) * DP;
    const unsigned short* kn_b = kn + (((long)bh) << 11) * DP;
    const unsigned short* vt_b = vt + (long)bh * DV * S_;

    bf16x8 qf[3];
    #pragma unroll
    for (int c = 0; c < 3; ++c)
        qf[c] = *(const bf16x8*)(qn_b + (long)(q0w + l16) * DP + c * 32 + quad * 8);

    f32x4 o[5];
    float den[4];
    #pragma unroll
    for (int dt = 0; dt < 5; ++dt) { o[dt][0]=0.f; o[dt][1]=0.f; o[dt][2]=0.f; o[dt][3]=0.f; }
    #pragma unroll
    for (int r = 0; r < 4; ++r) den[r] = 0.f;

    unsigned* Ps = lds + PBASE + w * (16 * PW);

    for (int kt = 0; kt < ntiles; ++kt) {
        const int k0 = kt * 64;
        __syncthreads();
        // stage K: 64 rows x 48 words; row r holds key 32*(r>>5)+2*(r&15)+((r>>4)&1)
        #pragma unroll
        for (int ii = 0; ii < 3; ++ii) {
            const int i = tid + ii * 256;
            const int r = i / 12, seg = i - r * 12;
            const int key = k0 + 32 * (r >> 5) + 2 * (r & 15) + ((r >> 4) & 1);
            *(uint4*)(lds + r * KS + seg * 4) = *(const uint4*)(kn_b + (long)key * DP + seg * 8);
        }
        // stage Vt: 80 rows x 32 words (natural key order)
        for (int i = tid; i < 640; i += 256) {
            const int rr = i >> 3, seg = i & 7;
            *(uint4*)(lds + VBASE + rr * VS + seg * 4) =
                *(const uint4*)(vt_b + (((long)rr) << 11) + k0 + seg * 8);
        }
        __syncthreads();

        f32x4 acc[4];
        #pragma unroll
        for (int G = 0; G < 4; ++G) { acc[G][0]=0.f; acc[G][1]=0.f; acc[G][2]=0.f; acc[G][3]=0.f; }
        #pragma unroll
        for (int c = 0; c < 3; ++c)
            #pragma unroll
            for (int G = 0; G < 4; ++G) {
                const bf16x8 kf = *(const bf16x8*)(lds + (16 * G + l16) * KS + c * 16 + quad * 4);
                acc[G] = mfma16(qf[c], kf, acc[G]);
            }
        // exp + pack P (keys for acc[2*g2+n][r]: 32*g2 + 2*l16 + n)
        #pragma unroll
        for (int g2 = 0; g2 < 2; ++g2) {
            const int kb = k0 + 32 * g2 + 2 * l16;
            #pragma unroll
            for (int r = 0; r < 4; ++r) {
                const int qa = q0w + quad * 4 + r;
                float p0 = acc[2 * g2][r], p1 = acc[2 * g2 + 1][r];
                p0 = (!causal || kb     <= qa) ? __expf(p0) : 0.f;
                p1 = (!causal || kb + 1 <= qa) ? __expf(p1) : 0.f;
                const __bf16 pb0 = (__bf16)p0, pb1 = (__bf16)p1;
                den[r] += (float)pb0 + (float)pb1;
                Ps[(quad * 4 + r) * PW + g2 * 16 + l16] =
                    (unsigned)__builtin_bit_cast(unsigned short, pb0) |
                    ((unsigned)__builtin_bit_cast(unsigned short, pb1) << 16);
            }
        }
        // PV: P round-trip (per-wave region; same-wave LDS ordering)
        const bf16x8 pa0 = *(const bf16x8*)(Ps + l16 * PW + quad * 4);
        const bf16x8 pa1 = *(const bf16x8*)(Ps + l16 * PW + 16 + quad * 4);
        #pragma unroll
        for (int dt = 0; dt < 5; ++dt) {
            const bf16x8 vf0 = *(const bf16x8*)(lds + VBASE + (dt * 16 + l16) * VS + quad * 4);
            const bf16x8 vf1 = *(const bf16x8*)(lds + VBASE + (dt * 16 + l16) * VS + 16 + quad * 4);
            o[dt] = mfma16(pa0, vf0, o[dt]);
            o[dt] = mfma16(pa1, vf1, o[dt]);
        }
    }

    #pragma unroll
    for (int r = 0; r < 4; ++r)
        #pragma unroll
        for (int x = 1; x < 16; x <<= 1) den[r] += __shfl_xor(den[r], x);

    if (!causal) {  // diagonal self-key k == q (window rows)
        float* PsD = (float*)Ps;
        float sp = 0.f;
        #pragma unroll
        for (int c = 0; c < 3; ++c) {
            const bf16x8 kd = *(const bf16x8*)(kn_b + (long)(q0w + l16) * DP + c * 32 + quad * 8);
            #pragma unroll
            for (int j = 0; j < 8; ++j) sp += (float)qf[c][j] * (float)kd[j];
        }
        sp += __shfl_xor(sp, 16);
        sp += __shfl_xor(sp, 32);
        if (quad == 0) PsD[l16] = __expf(sp);
        #pragma unroll
        for (int r = 0; r < 4; ++r) {
            const float pd = PsD[quad * 4 + r];
            den[r] += pd;
            const int qa = q0w + quad * 4 + r;
            #pragma unroll
            for (int dt = 0; dt < 5; ++dt) {
                const unsigned short uv = vt_b[(((long)(dt * 16 + l16)) << 11) + qa];
                o[dt][r] += pd * (float)__builtin_bit_cast(__bf16, uv);
            }
        }
    }

    #pragma unroll
    for (int r = 0; r < 4; ++r) {
        const float inv = 1.f / den[r];
        const int qa = q0w + quad * 4 + r;
        float* orow = out + ((long)(bh * S_ + qa)) * D_;
        #pragma unroll
        for (int dt = 0; dt < 5; ++dt) {
            const int dim = dt * 16 + l16;
            if (dim < D_) orow[dim] = o[dt][r] * inv;
        }
    }
}

extern "C" void kernel_launch(void* const* d_in, const int* in_sizes, int n_in,
                              void* d_out, int out_size, void* d_ws, size_t ws_size,
                              hipStream_t stream) {
    const float* q        = (const float*)d_in[0];
    const float* k        = (const float*)d_in[1];
    const float* v        = (const float*)d_in[2];
    const float* pos      = (const float*)d_in[3];
    const float* pos_orig = (const float*)d_in[4];
    const float* time_    = (const float*)d_in[5];
    const float* freqs    = (const float*)d_in[6];
    const float* t_freqs  = (const float*)d_in[7];
    const float* scale    = (const float*)d_in[8];
    float* out = (float*)d_out;

    unsigned* qn = (unsigned*)d_ws;
    unsigned* kn = qn + (size_t)B_ * H_ * S_ * 48;
    unsigned short* vt = (unsigned short*)(kn + (size_t)B_ * H_ * S_ * 48);

    pre_kernel<<<dim3(NPREP2 + NVT), dim3(256), 0, stream>>>(
        q, k, v, pos, pos_orig, time_, freqs, t_freqs, scale, qn, kn, vt, out);
    attn_kernel<<<dim3((S_ - LP) / 64, B_ * H_), dim3(256), 0, stream>>>(
        (const unsigned short*)qn, (const unsigned short*)kn, vt, out);
}